// Round 2
// baseline (473.871 us; speedup 1.0000x reference)
//
#include <hip/hip_runtime.h>
#include <type_traits>

#define NN 100000
#define NE 1600000
#define DF 128

typedef unsigned short ushort_t;
typedef unsigned int uint_t;
typedef __bf16 bf16x8 __attribute__((ext_vector_type(8)));
typedef float f32x4 __attribute__((ext_vector_type(4)));

union ABFrag { uint4 u; bf16x8 v; ushort_t s[8]; };

__device__ __forceinline__ float bf2f(ushort_t u) {
    uint_t v = ((uint_t)u) << 16;
    float f;
    __builtin_memcpy(&f, &v, 4);
    return f;
}

__device__ __forceinline__ ushort_t f2bf(float f) {
    uint_t u;
    __builtin_memcpy(&u, &f, 4);
    uint_t rounding = 0x7FFFu + ((u >> 16) & 1u);
    u += rounding;
    return (ushort_t)(u >> 16);
}

// ---------------------------------------------------------------- detect int64 edge_index
// int64 little-endian node ids < 2^31 -> odd 32-bit words of first 64 are all 0.
// int32 random node ids: probability all 32 odd words are 0 is ~0.
__global__ void k_detect(const int* ei, int* flag) {
    int l = threadIdx.x;  // 64 threads
    int v = ei[l];
    bool ok = ((l & 1) == 0) || (v == 0);
    unsigned long long m = __ballot(ok);
    if (l == 0) flag[0] = (m == 0xFFFFFFFFFFFFFFFFULL) ? 1 : 0;
}

__device__ __forceinline__ void load_edge(const int* ei, int is64, int e, int& s, int& d) {
    if (is64) {
        const long long* p = (const long long*)ei;
        s = (int)p[e];
        d = (int)p[NE + e];
    } else {
        s = ei[e];
        d = ei[NE + e];
    }
}

// ---------------------------------------------------------------- zero counts
__global__ void k_zero(int* cnt) {
    int i = blockIdx.x * 256 + threadIdx.x;
    if (i < NN) cnt[i] = 0;
}

// ---------------------------------------------------------------- degree histogram
__global__ void k_deg(const int* ei, const int* flag, int* cnt) {
    int is64 = flag[0];
    int e = blockIdx.x * 256 + threadIdx.x;
    if (e < NE) {
        int s, d;
        load_edge(ei, is64, e, s, d);
        atomicAdd(&cnt[d], 1);
    }
}

// ---------------------------------------------------------------- scan phase 1
__global__ void k_scan1(const int* cnt, int* rs, int* bsum) {
    __shared__ int sm[256];
    int t = threadIdx.x;
    int i = blockIdx.x * 256 + t;
    int v = (i < NN) ? cnt[i] : 0;
    sm[t] = v;
    __syncthreads();
    for (int o = 1; o < 256; o <<= 1) {
        int add = (t >= o) ? sm[t - o] : 0;
        __syncthreads();
        sm[t] += add;
        __syncthreads();
    }
    if (i < NN) rs[i] = sm[t] - v;  // exclusive within block
    if (t == 255) bsum[blockIdx.x] = sm[255];
}

// ---------------------------------------------------------------- scan phase 2 (block sums)
__global__ void k_scan2(const int* bsum, int* boff) {
    __shared__ int sm[512];
    const int NB = (NN + 255) / 256;  // 391
    int t = threadIdx.x;
    int v = (t < NB) ? bsum[t] : 0;
    sm[t] = v;
    __syncthreads();
    for (int o = 1; o < 512; o <<= 1) {
        int add = (t >= o) ? sm[t - o] : 0;
        __syncthreads();
        sm[t] += add;
        __syncthreads();
    }
    boff[t] = sm[t] - v;  // exclusive
}

// ---------------------------------------------------------------- scan phase 3 (apply offsets)
__global__ void k_scan3(int* rs, int* cur, const int* boff) {
    int i = blockIdx.x * 256 + threadIdx.x;
    if (i < NN) {
        int v = rs[i] + boff[i >> 8];
        rs[i] = v;
        cur[i] = v;
    } else if (i == NN) {
        rs[NN] = NE;
    }
}

// ---------------------------------------------------------------- counting-sort scatter
__global__ void k_scatter(const int* ei, const int* flag, int* cur, int* esrc) {
    int is64 = flag[0];
    int e = blockIdx.x * 256 + threadIdx.x;
    if (e < NE) {
        int s, d;
        load_edge(ei, is64, e, s, d);
        int pos = atomicAdd(&cur[d], 1);
        esrc[pos] = s;
    }
}

// ---------------------------------------------------------------- f32 -> bf16 cast (x -> xb)
__global__ void k_cast(const float* __restrict__ src, ushort_t* __restrict__ dst, int n4) {
    int i = blockIdx.x * 256 + threadIdx.x;
    if (i < n4) {
        float4 f = ((const float4*)src)[i];
        uint2 o;
        o.x = (uint_t)f2bf(f.x) | ((uint_t)f2bf(f.y) << 16);
        o.y = (uint_t)f2bf(f.z) | ((uint_t)f2bf(f.w) << 16);
        ((uint2*)dst)[i] = o;
    }
}

// ---------------------------------------------------------------- pack f32 weights -> bf16 B-frag layout
// dst[((s*NT+t)*64+lane)*8+j] = W_{s<4?l:r}[((s&3)*32 + (lane>>4)*8 + j)*NC + t*16 + (lane&15)]
__global__ void k_packW(const float* Wl, const float* Wr, ushort_t* dst, int NT) {
    int NC = NT * 16;
    int total = 8 * NT * 512;
    int idx = blockIdx.x * 256 + threadIdx.x;
    if (idx >= total) return;
    int j = idx & 7;
    int lane = (idx >> 3) & 63;
    int rem = idx / 512;
    int t = rem % NT;
    int s = rem / NT;
    int quad = lane >> 4, l16 = lane & 15;
    int k = (s & 3) * 32 + quad * 8 + j;
    int n = t * 16 + l16;
    const float* W = (s < 4) ? Wl : Wr;
    dst[idx] = f2bf(W[k * NC + n]);
}

// ---------------------------------------------------------------- mean aggregation: one wave per node
// feat is bf16 [NN,128]; lane i holds features 2i, 2i+1 (4B/lane -> 256B/row coalesced)
__global__ __launch_bounds__(256) void k_agg(const ushort_t* __restrict__ feat,
                                             const int* __restrict__ rs,
                                             const int* __restrict__ esrc,
                                             ushort_t* __restrict__ outm) {
    int wv = threadIdx.x >> 6;
    int lane = threadIdx.x & 63;
    int n = blockIdx.x * 4 + wv;
    if (n >= NN) return;
    int s0 = rs[n], s1 = rs[n + 1];
    float a0 = 0.f, a1 = 0.f;
    for (int base = s0; base < s1; base += 64) {
        int c = s1 - base;
        if (c > 64) c = 64;
        int my = (lane < c) ? esrc[base + lane] : 0;
        int e = 0;
        for (; e + 4 <= c; e += 4) {
            int r0 = __shfl(my, e);
            int r1 = __shfl(my, e + 1);
            int r2 = __shfl(my, e + 2);
            int r3 = __shfl(my, e + 3);
            uint_t v0 = *(const uint_t*)(feat + (size_t)r0 * DF + lane * 2);
            uint_t v1 = *(const uint_t*)(feat + (size_t)r1 * DF + lane * 2);
            uint_t v2 = *(const uint_t*)(feat + (size_t)r2 * DF + lane * 2);
            uint_t v3 = *(const uint_t*)(feat + (size_t)r3 * DF + lane * 2);
            a0 += bf2f((ushort_t)(v0 & 0xffff)) + bf2f((ushort_t)(v1 & 0xffff)) +
                  bf2f((ushort_t)(v2 & 0xffff)) + bf2f((ushort_t)(v3 & 0xffff));
            a1 += bf2f((ushort_t)(v0 >> 16)) + bf2f((ushort_t)(v1 >> 16)) +
                  bf2f((ushort_t)(v2 >> 16)) + bf2f((ushort_t)(v3 >> 16));
        }
        for (; e < c; ++e) {
            int r = __shfl(my, e);
            uint_t v = *(const uint_t*)(feat + (size_t)r * DF + lane * 2);
            a0 += bf2f((ushort_t)(v & 0xffff));
            a1 += bf2f((ushort_t)(v >> 16));
        }
    }
    int deg = s1 - s0;
    float inv = 1.0f / (float)(deg > 0 ? deg : 1);
    a0 *= inv;
    a1 *= inv;
    uint_t o = (uint_t)f2bf(a0) | ((uint_t)f2bf(a1) << 16);
    *(uint_t*)(outm + (size_t)n * DF + lane * 2) = o;
}

// ---------------------------------------------------------------- MFMA GEMM
// C[NN, NT*16] = [A0 | A1] (each bf16 [NN,128]) @ packed bf16 weights, + f32 bias,
// optional relu; OutT = ushort_t (bf16) or float.
// mfma_f32_16x16x32_bf16 layouts (HW-verified):
//   A: lane holds A[m=lane&15][k=(lane>>4)*8+j], j=0..7
//   B: lane holds B[k=(lane>>4)*8+j][n=lane&15]
//   C/D: col=lane&15, row=(lane>>4)*4+reg
template <int NT, bool RELU, typename OutT>
__global__ __launch_bounds__(256) void k_gemm(const ushort_t* __restrict__ A0,
                                              const ushort_t* __restrict__ A1,
                                              const ushort_t* __restrict__ Wpk,
                                              const float* __restrict__ bias,
                                              OutT* __restrict__ out) {
    const int NC = NT * 16;
    int warp = threadIdx.x >> 6;
    int lane = threadIdx.x & 63;
    int quad = lane >> 4;
    int l16 = lane & 15;
    int m0 = blockIdx.x * 64 + warp * 16;

    int rowA = m0 + l16;
    if (rowA >= NN) rowA = NN - 1;  // clamp; OOB rows never stored
    const int kofs = quad * 8;

    f32x4 acc[NT];
#pragma unroll
    for (int t = 0; t < NT; t++) acc[t] = (f32x4){0.f, 0.f, 0.f, 0.f};

#pragma unroll
    for (int s = 0; s < 8; s++) {
        const ushort_t* Ab = (s < 4) ? A0 : A1;
        int kk = (s & 3) * 32 + kofs;
        ABFrag a;
        a.u = *(const uint4*)(Ab + (size_t)rowA * DF + kk);
#pragma unroll
        for (int t = 0; t < NT; t++) {
            ABFrag b;
            b.u = *(const uint4*)(Wpk + ((size_t)(s * NT + t) * 64 + lane) * 8);
            acc[t] = __builtin_amdgcn_mfma_f32_16x16x32_bf16(a.v, b.v, acc[t], 0, 0, 0);
        }
    }

#pragma unroll
    for (int t = 0; t < NT; t++) {
        int col = t * 16 + l16;
        float bv = bias[col];
#pragma unroll
        for (int r = 0; r < 4; r++) {
            int row = m0 + quad * 4 + r;
            if (row < NN) {
                float v = acc[t][r] + bv;
                if (RELU) v = fmaxf(v, 0.f);
                if constexpr (std::is_same<OutT, ushort_t>::value)
                    out[(size_t)row * NC + col] = f2bf(v);
                else
                    out[(size_t)row * NC + col] = v;
            }
        }
    }
}

// ---------------------------------------------------------------- launcher
extern "C" void kernel_launch(void* const* d_in, const int* in_sizes, int n_in,
                              void* d_out, int out_size, void* d_ws, size_t ws_size,
                              hipStream_t stream) {
    const float* x   = (const float*)d_in[0];
    const int*   ei  = (const int*)d_in[1];
    const float* Wl0 = (const float*)d_in[2];
    const float* bl0 = (const float*)d_in[3];
    const float* Wr0 = (const float*)d_in[4];
    const float* Wl1 = (const float*)d_in[5];
    const float* bl1 = (const float*)d_in[6];
    const float* Wr1 = (const float*)d_in[7];
    float* out = (float*)d_out;

    char* ws = (char*)d_ws;
    size_t off = 0;
    auto alloc = [&](size_t b) {
        size_t o = off;
        off += (b + 255) & ~(size_t)255;
        return o;
    };
    int* flag = (int*)(ws + alloc(64));
    int* rs   = (int*)(ws + alloc((size_t)(NN + 1) * 4));
    int* cur  = (int*)(ws + alloc((size_t)NN * 4));
    int* bsum = (int*)(ws + alloc(512 * 4));
    int* boff = (int*)(ws + alloc(512 * 4));
    int* esrc = (int*)(ws + alloc((size_t)NE * 4));
    ushort_t* pw0  = (ushort_t*)(ws + alloc((size_t)8 * 8 * 512 * 2));
    ushort_t* pw1  = (ushort_t*)(ws + alloc((size_t)8 * 4 * 512 * 2));
    ushort_t* xb   = (ushort_t*)(ws + alloc((size_t)NN * DF * 2));
    ushort_t* mean = (ushort_t*)(ws + alloc((size_t)NN * DF * 2));
    ushort_t* h    = (ushort_t*)(ws + alloc((size_t)NN * DF * 2));

    const int GB_N = (NN + 255) / 256;       // 391
    const int GB_N1 = (NN + 1 + 255) / 256;  // 392
    const int GB_E = (NE + 255) / 256;       // 6250
    const int N4 = NN * DF / 4;              // 3.2M

    k_detect<<<1, 64, 0, stream>>>(ei, flag);
    k_zero<<<GB_N, 256, 0, stream>>>(cur);
    k_deg<<<GB_E, 256, 0, stream>>>(ei, flag, cur);
    k_scan1<<<GB_N, 256, 0, stream>>>(cur, rs, bsum);
    k_scan2<<<1, 512, 0, stream>>>(bsum, boff);
    k_scan3<<<GB_N1, 256, 0, stream>>>(rs, cur, boff);
    k_scatter<<<GB_E, 256, 0, stream>>>(ei, flag, cur, esrc);
    k_cast<<<(N4 + 255) / 256, 256, 0, stream>>>(x, xb, N4);
    k_packW<<<(8 * 8 * 512 + 255) / 256, 256, 0, stream>>>(Wl0, Wr0, pw0, 8);
    k_packW<<<(8 * 4 * 512 + 255) / 256, 256, 0, stream>>>(Wl1, Wr1, pw1, 4);

    k_agg<<<NN / 4, 256, 0, stream>>>(xb, rs, esrc, mean);
    k_gemm<8, true, ushort_t><<<(NN + 63) / 64, 256, 0, stream>>>(mean, xb, pw0, bl0, h);
    k_agg<<<NN / 4, 256, 0, stream>>>(h, rs, esrc, mean);
    k_gemm<4, false, float><<<(NN + 63) / 64, 256, 0, stream>>>(mean, h, pw1, bl1, out);
}

// Round 3
// 332.107 us; speedup vs baseline: 1.4269x; 1.4269x over previous
//
#include <hip/hip_runtime.h>
#include <type_traits>

#define NN 100000
#define NE 1600000
#define DF 128
#define NBKT 196        // ceil(100000 / 512) node buckets
#define BKT_SHIFT 9     // 512 nodes per bucket
#define EPB 6250        // edges per block in bucket passes (256 blocks * 6250 = NE exactly)

typedef unsigned short ushort_t;
typedef unsigned int uint_t;
typedef __bf16 bf16x8 __attribute__((ext_vector_type(8)));
typedef float f32x4 __attribute__((ext_vector_type(4)));

union ABFrag { uint4 u; bf16x8 v; ushort_t s[8]; };

__device__ __forceinline__ float bf2f(ushort_t u) {
    uint_t v = ((uint_t)u) << 16;
    float f;
    __builtin_memcpy(&f, &v, 4);
    return f;
}

__device__ __forceinline__ ushort_t f2bf(float f) {
    uint_t u;
    __builtin_memcpy(&u, &f, 4);
    uint_t rounding = 0x7FFFu + ((u >> 16) & 1u);
    u += rounding;
    return (ushort_t)(u >> 16);
}

// ---------------------------------------------------------------- detect int64 edge_index
__global__ void k_detect(const int* ei, int* flag) {
    int l = threadIdx.x;  // 64 threads
    int v = ei[l];
    bool ok = ((l & 1) == 0) || (v == 0);
    unsigned long long m = __ballot(ok);
    if (l == 0) flag[0] = (m == 0xFFFFFFFFFFFFFFFFULL) ? 1 : 0;
}

// ---------------------------------------------------------------- pass A: per-(block,bucket) histogram
// M[bkt*256 + blk] = #edges of block blk whose dst falls in bucket bkt. No global atomics.
__global__ __launch_bounds__(256) void k_bktcnt(const int* __restrict__ ei,
                                                const int* __restrict__ flag,
                                                int* __restrict__ M) {
    __shared__ int cnt[NBKT];
    int t = threadIdx.x, blk = blockIdx.x;
    for (int i = t; i < NBKT; i += 256) cnt[i] = 0;
    __syncthreads();
    int e0 = blk * EPB;
    if (flag[0]) {
        const long long* p = (const long long*)ei;
        for (int i = t; i < EPB; i += 256) {
            int d = (int)p[(size_t)NE + e0 + i];
            atomicAdd(&cnt[d >> BKT_SHIFT], 1);
        }
    } else {
        for (int i = t; i < EPB; i += 256) {
            int d = ei[NE + e0 + i];
            atomicAdd(&cnt[d >> BKT_SHIFT], 1);
        }
    }
    __syncthreads();
    for (int i = t; i < NBKT; i += 256) M[i * 256 + blk] = cnt[i];
}

// ---------------------------------------------------------------- per-bucket column scan over 256 blocks
__global__ __launch_bounds__(256) void k_colscan(int* __restrict__ M, int* __restrict__ colsum) {
    __shared__ int sm[256];
    int t = threadIdx.x, b = blockIdx.x;
    int v = M[b * 256 + t];
    sm[t] = v;
    __syncthreads();
    for (int o = 1; o < 256; o <<= 1) {
        int add = (t >= o) ? sm[t - o] : 0;
        __syncthreads();
        sm[t] += add;
        __syncthreads();
    }
    M[b * 256 + t] = sm[t] - v;  // exclusive offset of block t within bucket b
    if (t == 255) colsum[b] = sm[255];
}

// ---------------------------------------------------------------- scan bucket totals -> bkbase[0..NBKT]
__global__ __launch_bounds__(256) void k_bktscan(const int* __restrict__ colsum,
                                                 int* __restrict__ bkbase, int* __restrict__ rs) {
    __shared__ int sm[256];
    int t = threadIdx.x;
    int v = (t < NBKT) ? colsum[t] : 0;
    sm[t] = v;
    __syncthreads();
    for (int o = 1; o < 256; o <<= 1) {
        int add = (t >= o) ? sm[t - o] : 0;
        __syncthreads();
        sm[t] += add;
        __syncthreads();
    }
    if (t <= NBKT) bkbase[t] = sm[t] - v;  // exclusive; bkbase[NBKT] == NE
    if (t == 0) rs[NN] = NE;
}

// ---------------------------------------------------------------- pass B: scatter (src,dst) into bucket regions
// Deterministic reservation: block blk's slice in bucket b is [bkbase[b]+M[b*256+blk], +cnt).
__global__ __launch_bounds__(256) void k_bktscatter(const int* __restrict__ ei,
                                                    const int* __restrict__ flag,
                                                    const int* __restrict__ M,
                                                    const int* __restrict__ bkbase,
                                                    uint2* __restrict__ tmp) {
    __shared__ int cur[NBKT];
    int t = threadIdx.x, blk = blockIdx.x;
    for (int i = t; i < NBKT; i += 256) cur[i] = bkbase[i] + M[i * 256 + blk];
    __syncthreads();
    int e0 = blk * EPB;
    if (flag[0]) {
        const long long* p = (const long long*)ei;
        for (int i = t; i < EPB; i += 256) {
            int e = e0 + i;
            int s = (int)p[e], d = (int)p[(size_t)NE + e];
            int pos = atomicAdd(&cur[d >> BKT_SHIFT], 1);
            tmp[pos] = make_uint2((uint_t)s, (uint_t)d);
        }
    } else {
        for (int i = t; i < EPB; i += 256) {
            int e = e0 + i;
            int s = ei[e], d = ei[NE + e];
            int pos = atomicAdd(&cur[d >> BKT_SHIFT], 1);
            tmp[pos] = make_uint2((uint_t)s, (uint_t)d);
        }
    }
}

// ---------------------------------------------------------------- pass C: per-bucket node sort -> rs + esrc
__global__ __launch_bounds__(256) void k_bktsort(const uint2* __restrict__ tmp,
                                                 const int* __restrict__ bkbase,
                                                 int* __restrict__ rs, int* __restrict__ esrc) {
    __shared__ int hist[512];
    __shared__ int curp[512];
    int t = threadIdx.x, b = blockIdx.x;
    int nbase = b << BKT_SHIFT;
    int bb = bkbase[b], be = bkbase[b + 1];
    hist[t] = 0;
    hist[t + 256] = 0;
    __syncthreads();
    for (int i = bb + t; i < be; i += 256)
        atomicAdd(&hist[(int)tmp[i].y - nbase], 1);
    __syncthreads();
    int ov0 = hist[t], ov1 = hist[t + 256];
    for (int o = 1; o < 512; o <<= 1) {
        int v0 = (t >= o) ? hist[t - o] : 0;
        int v1 = (t + 256 >= o) ? hist[t + 256 - o] : 0;
        __syncthreads();
        hist[t] += v0;
        hist[t + 256] += v1;
        __syncthreads();
    }
    int ex0 = bb + hist[t] - ov0;        // exclusive scan -> start of node t's run
    int ex1 = bb + hist[t + 256] - ov1;
    int n0 = nbase + t, n1 = nbase + t + 256;
    if (n0 < NN) rs[n0] = ex0;
    if (n1 < NN) rs[n1] = ex1;
    curp[t] = ex0;
    curp[t + 256] = ex1;
    __syncthreads();
    for (int i = bb + t; i < be; i += 256) {
        uint2 pr = tmp[i];
        int pos = atomicAdd(&curp[(int)pr.y - nbase], 1);
        esrc[pos] = (int)pr.x;  // bucket's esrc slice (~32KB) is L2-resident -> full-line writebacks
    }
}

// ---------------------------------------------------------------- f32 -> bf16 cast (x -> xb)
__global__ void k_cast(const float* __restrict__ src, ushort_t* __restrict__ dst, int n4) {
    int i = blockIdx.x * 256 + threadIdx.x;
    if (i < n4) {
        float4 f = ((const float4*)src)[i];
        uint2 o;
        o.x = (uint_t)f2bf(f.x) | ((uint_t)f2bf(f.y) << 16);
        o.y = (uint_t)f2bf(f.z) | ((uint_t)f2bf(f.w) << 16);
        ((uint2*)dst)[i] = o;
    }
}

// ---------------------------------------------------------------- pack f32 weights -> bf16 B-frag layout
__global__ void k_packW(const float* Wl, const float* Wr, ushort_t* dst, int NT) {
    int NC = NT * 16;
    int total = 8 * NT * 512;
    int idx = blockIdx.x * 256 + threadIdx.x;
    if (idx >= total) return;
    int j = idx & 7;
    int lane = (idx >> 3) & 63;
    int rem = idx / 512;
    int t = rem % NT;
    int s = rem / NT;
    int quad = lane >> 4, l16 = lane & 15;
    int k = (s & 3) * 32 + quad * 8 + j;
    int n = t * 16 + l16;
    const float* W = (s < 4) ? Wl : Wr;
    dst[idx] = f2bf(W[k * NC + n]);
}

// ---------------------------------------------------------------- mean aggregation: one wave per node
__global__ __launch_bounds__(256) void k_agg(const ushort_t* __restrict__ feat,
                                             const int* __restrict__ rs,
                                             const int* __restrict__ esrc,
                                             ushort_t* __restrict__ outm) {
    int wv = threadIdx.x >> 6;
    int lane = threadIdx.x & 63;
    int n = blockIdx.x * 4 + wv;
    if (n >= NN) return;
    int s0 = rs[n], s1 = rs[n + 1];
    float a0 = 0.f, a1 = 0.f;
    for (int base = s0; base < s1; base += 64) {
        int c = s1 - base;
        if (c > 64) c = 64;
        int my = (lane < c) ? esrc[base + lane] : 0;
        int e = 0;
        for (; e + 4 <= c; e += 4) {
            int r0 = __shfl(my, e);
            int r1 = __shfl(my, e + 1);
            int r2 = __shfl(my, e + 2);
            int r3 = __shfl(my, e + 3);
            uint_t v0 = *(const uint_t*)(feat + (size_t)r0 * DF + lane * 2);
            uint_t v1 = *(const uint_t*)(feat + (size_t)r1 * DF + lane * 2);
            uint_t v2 = *(const uint_t*)(feat + (size_t)r2 * DF + lane * 2);
            uint_t v3 = *(const uint_t*)(feat + (size_t)r3 * DF + lane * 2);
            a0 += bf2f((ushort_t)(v0 & 0xffff)) + bf2f((ushort_t)(v1 & 0xffff)) +
                  bf2f((ushort_t)(v2 & 0xffff)) + bf2f((ushort_t)(v3 & 0xffff));
            a1 += bf2f((ushort_t)(v0 >> 16)) + bf2f((ushort_t)(v1 >> 16)) +
                  bf2f((ushort_t)(v2 >> 16)) + bf2f((ushort_t)(v3 >> 16));
        }
        for (; e < c; ++e) {
            int r = __shfl(my, e);
            uint_t v = *(const uint_t*)(feat + (size_t)r * DF + lane * 2);
            a0 += bf2f((ushort_t)(v & 0xffff));
            a1 += bf2f((ushort_t)(v >> 16));
        }
    }
    int deg = s1 - s0;
    float inv = 1.0f / (float)(deg > 0 ? deg : 1);
    a0 *= inv;
    a1 *= inv;
    uint_t o = (uint_t)f2bf(a0) | ((uint_t)f2bf(a1) << 16);
    *(uint_t*)(outm + (size_t)n * DF + lane * 2) = o;
}

// ---------------------------------------------------------------- MFMA GEMM
// C[NN, NT*16] = [A0 | A1] (each bf16 [NN,128]) @ packed bf16 weights, + f32 bias.
template <int NT, bool RELU, typename OutT>
__global__ __launch_bounds__(256) void k_gemm(const ushort_t* __restrict__ A0,
                                              const ushort_t* __restrict__ A1,
                                              const ushort_t* __restrict__ Wpk,
                                              const float* __restrict__ bias,
                                              OutT* __restrict__ out) {
    const int NC = NT * 16;
    int warp = threadIdx.x >> 6;
    int lane = threadIdx.x & 63;
    int quad = lane >> 4;
    int l16 = lane & 15;
    int m0 = blockIdx.x * 64 + warp * 16;

    int rowA = m0 + l16;
    if (rowA >= NN) rowA = NN - 1;  // clamp; OOB rows never stored
    const int kofs = quad * 8;

    f32x4 acc[NT];
#pragma unroll
    for (int t = 0; t < NT; t++) acc[t] = (f32x4){0.f, 0.f, 0.f, 0.f};

#pragma unroll
    for (int s = 0; s < 8; s++) {
        const ushort_t* Ab = (s < 4) ? A0 : A1;
        int kk = (s & 3) * 32 + kofs;
        ABFrag a;
        a.u = *(const uint4*)(Ab + (size_t)rowA * DF + kk);
#pragma unroll
        for (int t = 0; t < NT; t++) {
            ABFrag b;
            b.u = *(const uint4*)(Wpk + ((size_t)(s * NT + t) * 64 + lane) * 8);
            acc[t] = __builtin_amdgcn_mfma_f32_16x16x32_bf16(a.v, b.v, acc[t], 0, 0, 0);
        }
    }

#pragma unroll
    for (int t = 0; t < NT; t++) {
        int col = t * 16 + l16;
        float bv = bias[col];
#pragma unroll
        for (int r = 0; r < 4; r++) {
            int row = m0 + quad * 4 + r;
            if (row < NN) {
                float v = acc[t][r] + bv;
                if (RELU) v = fmaxf(v, 0.f);
                if constexpr (std::is_same<OutT, ushort_t>::value)
                    out[(size_t)row * NC + col] = f2bf(v);
                else
                    out[(size_t)row * NC + col] = v;
            }
        }
    }
}

// ---------------------------------------------------------------- launcher
extern "C" void kernel_launch(void* const* d_in, const int* in_sizes, int n_in,
                              void* d_out, int out_size, void* d_ws, size_t ws_size,
                              hipStream_t stream) {
    const float* x   = (const float*)d_in[0];
    const int*   ei  = (const int*)d_in[1];
    const float* Wl0 = (const float*)d_in[2];
    const float* bl0 = (const float*)d_in[3];
    const float* Wr0 = (const float*)d_in[4];
    const float* Wl1 = (const float*)d_in[5];
    const float* bl1 = (const float*)d_in[6];
    const float* Wr1 = (const float*)d_in[7];
    float* out = (float*)d_out;

    char* ws = (char*)d_ws;
    size_t off = 0;
    auto alloc = [&](size_t b) {
        size_t o = off;
        off += (b + 255) & ~(size_t)255;
        return o;
    };
    int* flag   = (int*)(ws + alloc(64));
    int* rs     = (int*)(ws + alloc((size_t)(NN + 1) * 4));
    int* M      = (int*)(ws + alloc((size_t)NBKT * 256 * 4));
    int* colsum = (int*)(ws + alloc((size_t)NBKT * 4));
    int* bkbase = (int*)(ws + alloc((size_t)(NBKT + 1) * 4));
    int* esrc   = (int*)(ws + alloc((size_t)NE * 4));
    ushort_t* pw0  = (ushort_t*)(ws + alloc((size_t)8 * 8 * 512 * 2));
    ushort_t* pw1  = (ushort_t*)(ws + alloc((size_t)8 * 4 * 512 * 2));
    ushort_t* xb   = (ushort_t*)(ws + alloc((size_t)NN * DF * 2));
    ushort_t* mean = (ushort_t*)(ws + alloc((size_t)NN * DF * 2));
    ushort_t* h    = (ushort_t*)(ws + alloc((size_t)NN * DF * 2));
    // tmp (12.8MB) aliases mean (25.6MB): tmp's last read (k_bktsort) precedes mean's
    // first write (k_agg). Keeps ws footprint ~84MB.
    uint2* tmp = (uint2*)mean;

    const int N4 = NN * DF / 4;  // 3.2M

    k_detect<<<1, 64, 0, stream>>>(ei, flag);
    k_bktcnt<<<256, 256, 0, stream>>>(ei, flag, M);
    k_colscan<<<NBKT, 256, 0, stream>>>(M, colsum);
    k_bktscan<<<1, 256, 0, stream>>>(colsum, bkbase, rs);
    k_bktscatter<<<256, 256, 0, stream>>>(ei, flag, M, bkbase, tmp);
    k_bktsort<<<NBKT, 256, 0, stream>>>(tmp, bkbase, rs, esrc);
    k_cast<<<(N4 + 255) / 256, 256, 0, stream>>>(x, xb, N4);
    k_packW<<<(8 * 8 * 512 + 255) / 256, 256, 0, stream>>>(Wl0, Wr0, pw0, 8);
    k_packW<<<(8 * 4 * 512 + 255) / 256, 256, 0, stream>>>(Wl1, Wr1, pw1, 4);

    k_agg<<<NN / 4, 256, 0, stream>>>(xb, rs, esrc, mean);
    k_gemm<8, true, ushort_t><<<(NN + 63) / 64, 256, 0, stream>>>(mean, xb, pw0, bl0, h);
    k_agg<<<NN / 4, 256, 0, stream>>>(h, rs, esrc, mean);
    k_gemm<4, false, float><<<(NN + 63) / 64, 256, 0, stream>>>(mean, h, pw1, bl1, out);
}

// Round 4
// 310.639 us; speedup vs baseline: 1.5255x; 1.0691x over previous
//
#include <hip/hip_runtime.h>
#include <type_traits>

#define NN 100000
#define NE 1600000
#define DF 128
#define NBKT 196        // ceil(100000 / 512) node buckets
#define BKT_SHIFT 9     // 512 nodes per bucket
#define EPB 6250        // edges per block in bucket passes (256 blocks * 6250 = NE exactly)

typedef unsigned short ushort_t;
typedef unsigned int uint_t;
typedef __bf16 bf16x8 __attribute__((ext_vector_type(8)));
typedef float f32x4 __attribute__((ext_vector_type(4)));

union ABFrag { uint4 u; bf16x8 v; ushort_t s[8]; };

__device__ __forceinline__ ushort_t f2bf(float f) {
    uint_t u;
    __builtin_memcpy(&u, &f, 4);
    uint_t rounding = 0x7FFFu + ((u >> 16) & 1u);
    u += rounding;
    return (ushort_t)(u >> 16);
}
__device__ __forceinline__ float lo_f(uint_t u) { return __uint_as_float(u << 16); }
__device__ __forceinline__ float hi_f(uint_t u) { return __uint_as_float(u & 0xffff0000u); }
__device__ __forceinline__ uint_t pack2(float a, float b) {
    return (uint_t)f2bf(a) | ((uint_t)f2bf(b) << 16);
}

// ---------------------------------------------------------------- detect int64 edge_index
__global__ void k_detect(const int* ei, int* flag) {
    int l = threadIdx.x;  // 64 threads
    int v = ei[l];
    bool ok = ((l & 1) == 0) || (v == 0);
    unsigned long long m = __ballot(ok);
    if (l == 0) flag[0] = (m == 0xFFFFFFFFFFFFFFFFULL) ? 1 : 0;
}

// ---------------------------------------------------------------- pass A: per-(block,bucket) histogram
__global__ __launch_bounds__(256) void k_bktcnt(const int* __restrict__ ei,
                                                const int* __restrict__ flag,
                                                int* __restrict__ M) {
    __shared__ int cnt[NBKT];
    int t = threadIdx.x, blk = blockIdx.x;
    for (int i = t; i < NBKT; i += 256) cnt[i] = 0;
    __syncthreads();
    int e0 = blk * EPB;
    if (flag[0]) {
        const long long* p = (const long long*)ei;
        for (int i = t; i < EPB; i += 256) {
            int d = (int)p[(size_t)NE + e0 + i];
            atomicAdd(&cnt[d >> BKT_SHIFT], 1);
        }
    } else {
        for (int i = t; i < EPB; i += 256) {
            int d = ei[NE + e0 + i];
            atomicAdd(&cnt[d >> BKT_SHIFT], 1);
        }
    }
    __syncthreads();
    for (int i = t; i < NBKT; i += 256) M[i * 256 + blk] = cnt[i];
}

// ---------------------------------------------------------------- per-bucket column scan over 256 blocks
__global__ __launch_bounds__(256) void k_colscan(int* __restrict__ M, int* __restrict__ colsum) {
    __shared__ int sm[256];
    int t = threadIdx.x, b = blockIdx.x;
    int v = M[b * 256 + t];
    sm[t] = v;
    __syncthreads();
    for (int o = 1; o < 256; o <<= 1) {
        int add = (t >= o) ? sm[t - o] : 0;
        __syncthreads();
        sm[t] += add;
        __syncthreads();
    }
    M[b * 256 + t] = sm[t] - v;  // exclusive offset of block t within bucket b
    if (t == 255) colsum[b] = sm[255];
}

// ---------------------------------------------------------------- scan bucket totals -> bkbase[0..NBKT]
__global__ __launch_bounds__(256) void k_bktscan(const int* __restrict__ colsum,
                                                 int* __restrict__ bkbase, int* __restrict__ rs) {
    __shared__ int sm[256];
    int t = threadIdx.x;
    int v = (t < NBKT) ? colsum[t] : 0;
    sm[t] = v;
    __syncthreads();
    for (int o = 1; o < 256; o <<= 1) {
        int add = (t >= o) ? sm[t - o] : 0;
        __syncthreads();
        sm[t] += add;
        __syncthreads();
    }
    if (t <= NBKT) bkbase[t] = sm[t] - v;  // exclusive; bkbase[NBKT] == NE
    if (t == 0) rs[NN] = NE;
}

// ---------------------------------------------------------------- pass B: scatter (src,dst) into bucket regions
__global__ __launch_bounds__(256) void k_bktscatter(const int* __restrict__ ei,
                                                    const int* __restrict__ flag,
                                                    const int* __restrict__ M,
                                                    const int* __restrict__ bkbase,
                                                    uint2* __restrict__ tmp) {
    __shared__ int cur[NBKT];
    int t = threadIdx.x, blk = blockIdx.x;
    for (int i = t; i < NBKT; i += 256) cur[i] = bkbase[i] + M[i * 256 + blk];
    __syncthreads();
    int e0 = blk * EPB;
    if (flag[0]) {
        const long long* p = (const long long*)ei;
        for (int i = t; i < EPB; i += 256) {
            int e = e0 + i;
            int s = (int)p[e], d = (int)p[(size_t)NE + e];
            int pos = atomicAdd(&cur[d >> BKT_SHIFT], 1);
            tmp[pos] = make_uint2((uint_t)s, (uint_t)d);
        }
    } else {
        for (int i = t; i < EPB; i += 256) {
            int e = e0 + i;
            int s = ei[e], d = ei[NE + e];
            int pos = atomicAdd(&cur[d >> BKT_SHIFT], 1);
            tmp[pos] = make_uint2((uint_t)s, (uint_t)d);
        }
    }
}

// ---------------------------------------------------------------- pass C: per-bucket node sort -> rs + esrc
__global__ __launch_bounds__(256) void k_bktsort(const uint2* __restrict__ tmp,
                                                 const int* __restrict__ bkbase,
                                                 int* __restrict__ rs, int* __restrict__ esrc) {
    __shared__ int hist[512];
    __shared__ int curp[512];
    int t = threadIdx.x, b = blockIdx.x;
    int nbase = b << BKT_SHIFT;
    int bb = bkbase[b], be = bkbase[b + 1];
    hist[t] = 0;
    hist[t + 256] = 0;
    __syncthreads();
    for (int i = bb + t; i < be; i += 256)
        atomicAdd(&hist[(int)tmp[i].y - nbase], 1);
    __syncthreads();
    int ov0 = hist[t], ov1 = hist[t + 256];
    for (int o = 1; o < 512; o <<= 1) {
        int v0 = (t >= o) ? hist[t - o] : 0;
        int v1 = (t + 256 >= o) ? hist[t + 256 - o] : 0;
        __syncthreads();
        hist[t] += v0;
        hist[t + 256] += v1;
        __syncthreads();
    }
    int ex0 = bb + hist[t] - ov0;
    int ex1 = bb + hist[t + 256] - ov1;
    int n0 = nbase + t, n1 = nbase + t + 256;
    if (n0 < NN) rs[n0] = ex0;
    if (n1 < NN) rs[n1] = ex1;
    curp[t] = ex0;
    curp[t + 256] = ex1;
    __syncthreads();
    for (int i = bb + t; i < be; i += 256) {
        uint2 pr = tmp[i];
        int pos = atomicAdd(&curp[(int)pr.y - nbase], 1);
        esrc[pos] = (int)pr.x;
    }
}

// ---------------------------------------------------------------- f32 -> bf16 cast (x -> xb, + zero row NN)
__global__ void k_cast(const float* __restrict__ src, ushort_t* __restrict__ dst, int n4) {
    int i = blockIdx.x * 256 + threadIdx.x;
    if (i < n4) {
        float4 f = ((const float4*)src)[i];
        uint2 o;
        o.x = pack2(f.x, f.y);
        o.y = pack2(f.z, f.w);
        ((uint2*)dst)[i] = o;
    } else if (i < n4 + 32) {
        ((uint2*)dst)[i] = make_uint2(0u, 0u);  // zero row NN (gather clamp target)
    }
}

// ---------------------------------------------------------------- pack layer-0 weights: [Wl0; Wr0] along K
// dst[((s*8+t)*64+lane)*8+j] = (s<4?Wl0:Wr0)[((s&3)*32 + quad*8 + j)*128 + t*16 + l16]
__global__ void k_packW0(const float* Wl, const float* Wr, ushort_t* dst) {
    int total = 8 * 8 * 512;
    int idx = blockIdx.x * 256 + threadIdx.x;
    if (idx >= total) return;
    int j = idx & 7;
    int lane = (idx >> 3) & 63;
    int rem = idx / 512;
    int t = rem % 8;
    int s = rem / 8;
    int quad = lane >> 4, l16 = lane & 15;
    int k = (s & 3) * 32 + quad * 8 + j;
    int n = t * 16 + l16;
    const float* W = (s < 4) ? Wl : Wr;
    dst[idx] = f2bf(W[k * 128 + n]);
}

// ---------------------------------------------------------------- pack layer-1 weights: [Wl1 | Wr1] along N
// dst[((s*8+t)*64+lane)*8+j] = (t<4?Wl1:Wr1)[(s*32 + quad*8 + j)*64 + (t&3)*16 + l16], s in 0..3
__global__ void k_packW1(const float* Wl, const float* Wr, ushort_t* dst) {
    int total = 4 * 8 * 512;
    int idx = blockIdx.x * 256 + threadIdx.x;
    if (idx >= total) return;
    int j = idx & 7;
    int lane = (idx >> 3) & 63;
    int rem = idx / 512;
    int t = rem % 8;
    int s = rem / 8;
    int quad = lane >> 4, l16 = lane & 15;
    int k = s * 32 + quad * 8 + j;
    int n = (t & 3) * 16 + l16;
    const float* W = (t < 4) ? Wl : Wr;
    dst[idx] = f2bf(W[k * 64 + n]);
}

// ---------------------------------------------------------------- zero tbuf row NN (after layer-1 GEMM)
__global__ void k_zrow2(ushort_t* tbuf) {
    int t = threadIdx.x;  // 64 threads
    if (t < 32) ((uint_t*)(tbuf + (size_t)NN * 64))[t] = 0u;
}

// ---------------------------------------------------------------- layer-0 mean aggregation
// 4 nodes per wave (16-lane groups); one dwordx4 load fetches one 256B row per group.
// feat has NN+1 rows; row NN is zero (inactive-lane clamp target).
__global__ __launch_bounds__(256) void k_agg0(const ushort_t* __restrict__ feat,
                                              const int* __restrict__ rs,
                                              const int* __restrict__ esrc,
                                              ushort_t* __restrict__ outm) {
    int wv = threadIdx.x >> 6;
    int lane = threadIdx.x & 63;
    int li = lane & 15;
    int gbase = lane & 48;
    int n = (blockIdx.x * 4 + wv) * 4 + (lane >> 4);  // 16 nodes/block
    int s0 = 0, deg = 0;
    if (n < NN) {
        s0 = rs[n];
        deg = rs[n + 1] - s0;
    }
    int md = deg;
    md = max(md, __shfl_xor(md, 16));
    md = max(md, __shfl_xor(md, 32));
    float acc[8] = {0.f, 0.f, 0.f, 0.f, 0.f, 0.f, 0.f, 0.f};
    const ushort_t* fb = feat + li * 8;
    int clampIdx = (deg > 0) ? deg - 1 : 0;
    for (int c = 0; c < md; c += 16) {
        int ii = c + li;
        if (ii > clampIdx) ii = clampIdx;
        int my = esrc[s0 + ii];
        int lim = md - c;
        if (lim > 16) lim = 16;
        int e = 0;
        for (; e + 4 <= lim; e += 4) {
            int r0 = __shfl(my, gbase + e);
            int r1 = __shfl(my, gbase + e + 1);
            int r2 = __shfl(my, gbase + e + 2);
            int r3 = __shfl(my, gbase + e + 3);
            r0 = (c + e < deg) ? r0 : NN;
            r1 = (c + e + 1 < deg) ? r1 : NN;
            r2 = (c + e + 2 < deg) ? r2 : NN;
            r3 = (c + e + 3 < deg) ? r3 : NN;
            uint4 v0 = *(const uint4*)(fb + (size_t)r0 * DF);
            uint4 v1 = *(const uint4*)(fb + (size_t)r1 * DF);
            uint4 v2 = *(const uint4*)(fb + (size_t)r2 * DF);
            uint4 v3 = *(const uint4*)(fb + (size_t)r3 * DF);
            acc[0] += lo_f(v0.x); acc[1] += hi_f(v0.x); acc[2] += lo_f(v0.y); acc[3] += hi_f(v0.y);
            acc[4] += lo_f(v0.z); acc[5] += hi_f(v0.z); acc[6] += lo_f(v0.w); acc[7] += hi_f(v0.w);
            acc[0] += lo_f(v1.x); acc[1] += hi_f(v1.x); acc[2] += lo_f(v1.y); acc[3] += hi_f(v1.y);
            acc[4] += lo_f(v1.z); acc[5] += hi_f(v1.z); acc[6] += lo_f(v1.w); acc[7] += hi_f(v1.w);
            acc[0] += lo_f(v2.x); acc[1] += hi_f(v2.x); acc[2] += lo_f(v2.y); acc[3] += hi_f(v2.y);
            acc[4] += lo_f(v2.z); acc[5] += hi_f(v2.z); acc[6] += lo_f(v2.w); acc[7] += hi_f(v2.w);
            acc[0] += lo_f(v3.x); acc[1] += hi_f(v3.x); acc[2] += lo_f(v3.y); acc[3] += hi_f(v3.y);
            acc[4] += lo_f(v3.z); acc[5] += hi_f(v3.z); acc[6] += lo_f(v3.w); acc[7] += hi_f(v3.w);
        }
        for (; e < lim; ++e) {
            int r = __shfl(my, gbase + e);
            r = (c + e < deg) ? r : NN;
            uint4 v = *(const uint4*)(fb + (size_t)r * DF);
            acc[0] += lo_f(v.x); acc[1] += hi_f(v.x); acc[2] += lo_f(v.y); acc[3] += hi_f(v.y);
            acc[4] += lo_f(v.z); acc[5] += hi_f(v.z); acc[6] += lo_f(v.w); acc[7] += hi_f(v.w);
        }
    }
    if (n < NN) {
        float inv = 1.0f / (float)(deg > 0 ? deg : 1);
        uint4 o;
        o.x = pack2(acc[0] * inv, acc[1] * inv);
        o.y = pack2(acc[2] * inv, acc[3] * inv);
        o.z = pack2(acc[4] * inv, acc[5] * inv);
        o.w = pack2(acc[6] * inv, acc[7] * inv);
        *(uint4*)(outm + (size_t)n * DF + li * 8) = o;
    }
}

// ---------------------------------------------------------------- layer-1 final: out = mean(gather(t)) + r
// 8 nodes per wave (8-lane groups); t rows are 64 bf16 = 128 B; r/out rows are 64 f32.
__global__ __launch_bounds__(256) void k_agg2(const ushort_t* __restrict__ tbuf,
                                              const float* __restrict__ rbuf,
                                              const int* __restrict__ rs,
                                              const int* __restrict__ esrc,
                                              float* __restrict__ out) {
    int wv = threadIdx.x >> 6;
    int lane = threadIdx.x & 63;
    int li = lane & 7;
    int gbase = lane & 56;
    int n = (blockIdx.x * 4 + wv) * 8 + (lane >> 3);  // 32 nodes/block
    int s0 = 0, deg = 0;
    if (n < NN) {
        s0 = rs[n];
        deg = rs[n + 1] - s0;
    }
    int md = deg;
    md = max(md, __shfl_xor(md, 8));
    md = max(md, __shfl_xor(md, 16));
    md = max(md, __shfl_xor(md, 32));
    float acc[8] = {0.f, 0.f, 0.f, 0.f, 0.f, 0.f, 0.f, 0.f};
    const ushort_t* fb = tbuf + li * 8;
    int clampIdx = (deg > 0) ? deg - 1 : 0;
    for (int c = 0; c < md; c += 8) {
        int ii = c + li;
        if (ii > clampIdx) ii = clampIdx;
        int my = esrc[s0 + ii];
        int lim = md - c;
        if (lim > 8) lim = 8;
        int e = 0;
        for (; e + 4 <= lim; e += 4) {
            int r0 = __shfl(my, gbase + e);
            int r1 = __shfl(my, gbase + e + 1);
            int r2 = __shfl(my, gbase + e + 2);
            int r3 = __shfl(my, gbase + e + 3);
            r0 = (c + e < deg) ? r0 : NN;
            r1 = (c + e + 1 < deg) ? r1 : NN;
            r2 = (c + e + 2 < deg) ? r2 : NN;
            r3 = (c + e + 3 < deg) ? r3 : NN;
            uint4 v0 = *(const uint4*)(fb + (size_t)r0 * 64);
            uint4 v1 = *(const uint4*)(fb + (size_t)r1 * 64);
            uint4 v2 = *(const uint4*)(fb + (size_t)r2 * 64);
            uint4 v3 = *(const uint4*)(fb + (size_t)r3 * 64);
            acc[0] += lo_f(v0.x); acc[1] += hi_f(v0.x); acc[2] += lo_f(v0.y); acc[3] += hi_f(v0.y);
            acc[4] += lo_f(v0.z); acc[5] += hi_f(v0.z); acc[6] += lo_f(v0.w); acc[7] += hi_f(v0.w);
            acc[0] += lo_f(v1.x); acc[1] += hi_f(v1.x); acc[2] += lo_f(v1.y); acc[3] += hi_f(v1.y);
            acc[4] += lo_f(v1.z); acc[5] += hi_f(v1.z); acc[6] += lo_f(v1.w); acc[7] += hi_f(v1.w);
            acc[0] += lo_f(v2.x); acc[1] += hi_f(v2.x); acc[2] += lo_f(v2.y); acc[3] += hi_f(v2.y);
            acc[4] += lo_f(v2.z); acc[5] += hi_f(v2.z); acc[6] += lo_f(v2.w); acc[7] += hi_f(v2.w);
            acc[0] += lo_f(v3.x); acc[1] += hi_f(v3.x); acc[2] += lo_f(v3.y); acc[3] += hi_f(v3.y);
            acc[4] += lo_f(v3.z); acc[5] += hi_f(v3.z); acc[6] += lo_f(v3.w); acc[7] += hi_f(v3.w);
        }
        for (; e < lim; ++e) {
            int r = __shfl(my, gbase + e);
            r = (c + e < deg) ? r : NN;
            uint4 v = *(const uint4*)(fb + (size_t)r * 64);
            acc[0] += lo_f(v.x); acc[1] += hi_f(v.x); acc[2] += lo_f(v.y); acc[3] += hi_f(v.y);
            acc[4] += lo_f(v.z); acc[5] += hi_f(v.z); acc[6] += lo_f(v.w); acc[7] += hi_f(v.w);
        }
    }
    if (n < NN) {
        float inv = 1.0f / (float)(deg > 0 ? deg : 1);
        const float4* rp = (const float4*)(rbuf + (size_t)n * 64 + li * 8);
        float4 ra = rp[0], rb = rp[1];
        float4 oa, ob;
        oa.x = acc[0] * inv + ra.x; oa.y = acc[1] * inv + ra.y;
        oa.z = acc[2] * inv + ra.z; oa.w = acc[3] * inv + ra.w;
        ob.x = acc[4] * inv + rb.x; ob.y = acc[5] * inv + rb.y;
        ob.z = acc[6] * inv + rb.z; ob.w = acc[7] * inv + rb.w;
        float4* op = (float4*)(out + (size_t)n * 64 + li * 8);
        op[0] = oa;
        op[1] = ob;
    }
}

// ---------------------------------------------------------------- layer-0 MFMA GEMM (K=256 concat)
// h[NN,128] = relu([mean | xb] @ [Wl0; Wr0] + b)
template <int NT, bool RELU, typename OutT>
__global__ __launch_bounds__(256) void k_gemm(const ushort_t* __restrict__ A0,
                                              const ushort_t* __restrict__ A1,
                                              const ushort_t* __restrict__ Wpk,
                                              const float* __restrict__ bias,
                                              OutT* __restrict__ out) {
    const int NC = NT * 16;
    int warp = threadIdx.x >> 6;
    int lane = threadIdx.x & 63;
    int quad = lane >> 4;
    int l16 = lane & 15;
    int m0 = blockIdx.x * 64 + warp * 16;

    int rowA = m0 + l16;
    if (rowA >= NN) rowA = NN - 1;
    const int kofs = quad * 8;

    f32x4 acc[NT];
#pragma unroll
    for (int t = 0; t < NT; t++) acc[t] = (f32x4){0.f, 0.f, 0.f, 0.f};

#pragma unroll
    for (int s = 0; s < 8; s++) {
        const ushort_t* Ab = (s < 4) ? A0 : A1;
        int kk = (s & 3) * 32 + kofs;
        ABFrag a;
        a.u = *(const uint4*)(Ab + (size_t)rowA * DF + kk);
#pragma unroll
        for (int t = 0; t < NT; t++) {
            ABFrag b;
            b.u = *(const uint4*)(Wpk + ((size_t)(s * NT + t) * 64 + lane) * 8);
            acc[t] = __builtin_amdgcn_mfma_f32_16x16x32_bf16(a.v, b.v, acc[t], 0, 0, 0);
        }
    }

#pragma unroll
    for (int t = 0; t < NT; t++) {
        int col = t * 16 + l16;
        float bv = bias[col];
#pragma unroll
        for (int r = 0; r < 4; r++) {
            int row = m0 + quad * 4 + r;
            if (row < NN) {
                float v = acc[t][r] + bv;
                if (RELU) v = fmaxf(v, 0.f);
                if constexpr (std::is_same<OutT, ushort_t>::value)
                    out[(size_t)row * NC + col] = f2bf(v);
                else
                    out[(size_t)row * NC + col] = v;
            }
        }
    }
}

// ---------------------------------------------------------------- layer-1 MFMA GEMM (K=128, dual out)
// [t|r] = h @ [Wl1|Wr1]; t -> bf16 tbuf (cols 0..63), r + bias -> f32 rbuf (cols 64..127)
__global__ __launch_bounds__(256) void k_gemm2(const ushort_t* __restrict__ A,
                                               const ushort_t* __restrict__ Wpk,
                                               const float* __restrict__ bias,
                                               ushort_t* __restrict__ tbuf,
                                               float* __restrict__ rbuf) {
    int warp = threadIdx.x >> 6;
    int lane = threadIdx.x & 63;
    int quad = lane >> 4;
    int l16 = lane & 15;
    int m0 = blockIdx.x * 64 + warp * 16;

    int rowA = m0 + l16;
    if (rowA >= NN) rowA = NN - 1;
    const int kofs = quad * 8;

    f32x4 acc[8];
#pragma unroll
    for (int t = 0; t < 8; t++) acc[t] = (f32x4){0.f, 0.f, 0.f, 0.f};

#pragma unroll
    for (int s = 0; s < 4; s++) {
        int kk = s * 32 + kofs;
        ABFrag a;
        a.u = *(const uint4*)(A + (size_t)rowA * DF + kk);
#pragma unroll
        for (int t = 0; t < 8; t++) {
            ABFrag b;
            b.u = *(const uint4*)(Wpk + ((size_t)(s * 8 + t) * 64 + lane) * 8);
            acc[t] = __builtin_amdgcn_mfma_f32_16x16x32_bf16(a.v, b.v, acc[t], 0, 0, 0);
        }
    }

#pragma unroll
    for (int t = 0; t < 8; t++) {
        int cc = (t & 3) * 16 + l16;  // column within the 64-wide half
        float bv = (t >= 4) ? bias[cc] : 0.f;
#pragma unroll
        for (int r = 0; r < 4; r++) {
            int row = m0 + quad * 4 + r;
            if (row < NN) {
                float v = acc[t][r];
                if (t < 4)
                    tbuf[(size_t)row * 64 + cc] = f2bf(v);
                else
                    rbuf[(size_t)row * 64 + cc] = v + bv;
            }
        }
    }
}

// ---------------------------------------------------------------- launcher
extern "C" void kernel_launch(void* const* d_in, const int* in_sizes, int n_in,
                              void* d_out, int out_size, void* d_ws, size_t ws_size,
                              hipStream_t stream) {
    const float* x   = (const float*)d_in[0];
    const int*   ei  = (const int*)d_in[1];
    const float* Wl0 = (const float*)d_in[2];
    const float* bl0 = (const float*)d_in[3];
    const float* Wr0 = (const float*)d_in[4];
    const float* Wl1 = (const float*)d_in[5];
    const float* bl1 = (const float*)d_in[6];
    const float* Wr1 = (const float*)d_in[7];
    float* out = (float*)d_out;

    char* ws = (char*)d_ws;
    size_t off = 0;
    auto alloc = [&](size_t b) {
        size_t o = off;
        off += (b + 255) & ~(size_t)255;
        return o;
    };
    int* flag   = (int*)(ws + alloc(64));
    int* rs     = (int*)(ws + alloc((size_t)(NN + 1) * 4));
    int* M      = (int*)(ws + alloc((size_t)NBKT * 256 * 4));
    int* colsum = (int*)(ws + alloc((size_t)NBKT * 4));
    int* bkbase = (int*)(ws + alloc((size_t)(NBKT + 1) * 4));
    int* esrc   = (int*)(ws + alloc((size_t)NE * 4));
    ushort_t* pw0  = (ushort_t*)(ws + alloc((size_t)8 * 8 * 512 * 2));
    ushort_t* pw1  = (ushort_t*)(ws + alloc((size_t)4 * 8 * 512 * 2));
    ushort_t* xb   = (ushort_t*)(ws + alloc((size_t)(NN + 1) * DF * 2));  // +1 zero row
    ushort_t* mean = (ushort_t*)(ws + alloc((size_t)NN * DF * 2));
    ushort_t* h    = (ushort_t*)(ws + alloc((size_t)NN * DF * 2));
    // Aliases (lifetimes disjoint, stream-ordered):
    //   tmp  (12.8MB, bktscatter->bktsort)  on mean (written first by k_agg0 afterwards)
    //   tbuf ((NN+1)*64 bf16, k_gemm2->k_agg2) on xb (dead after layer-0 GEMM)
    //   rbuf (NN*64 f32, k_gemm2->k_agg2)      on mean (dead after layer-0 GEMM)
    uint2* tmp = (uint2*)mean;
    ushort_t* tbuf = xb;
    float* rbuf = (float*)mean;

    const int N4 = NN * DF / 4;  // 3.2M uint2 pairs

    k_detect<<<1, 64, 0, stream>>>(ei, flag);
    k_bktcnt<<<256, 256, 0, stream>>>(ei, flag, M);
    k_colscan<<<NBKT, 256, 0, stream>>>(M, colsum);
    k_bktscan<<<1, 256, 0, stream>>>(colsum, bkbase, rs);
    k_bktscatter<<<256, 256, 0, stream>>>(ei, flag, M, bkbase, tmp);
    k_bktsort<<<NBKT, 256, 0, stream>>>(tmp, bkbase, rs, esrc);
    k_cast<<<(N4 + 32 + 255) / 256, 256, 0, stream>>>(x, xb, N4);
    k_packW0<<<(8 * 8 * 512 + 255) / 256, 256, 0, stream>>>(Wl0, Wr0, pw0);
    k_packW1<<<(4 * 8 * 512 + 255) / 256, 256, 0, stream>>>(Wl1, Wr1, pw1);

    k_agg0<<<NN / 16, 256, 0, stream>>>(xb, rs, esrc, mean);
    k_gemm<8, true, ushort_t><<<(NN + 63) / 64, 256, 0, stream>>>(mean, xb, pw0, bl0, h);
    k_gemm2<<<(NN + 63) / 64, 256, 0, stream>>>(h, pw1, bl1, tbuf, rbuf);
    k_zrow2<<<1, 64, 0, stream>>>(tbuf);
    k_agg2<<<(NN + 31) / 32, 256, 0, stream>>>(tbuf, rbuf, rs, esrc, out);
}

// Round 5
// 290.290 us; speedup vs baseline: 1.6324x; 1.0701x over previous
//
#include <hip/hip_runtime.h>
#include <type_traits>

#define NN 100000
#define NE 1600000
#define DF 128
#define NBKT 196        // ceil(100000 / 512) node buckets
#define BKT_SHIFT 9     // 512 nodes per bucket
#define EPB 6250        // edges per block in bucket passes (256 blocks * 6250 = NE exactly)

typedef unsigned short ushort_t;
typedef unsigned int uint_t;
typedef __bf16 bf16x8 __attribute__((ext_vector_type(8)));
typedef float f32x4 __attribute__((ext_vector_type(4)));

union ABFrag { uint4 u; bf16x8 v; ushort_t s[8]; };

__device__ __forceinline__ ushort_t f2bf(float f) {
    uint_t u;
    __builtin_memcpy(&u, &f, 4);
    uint_t rounding = 0x7FFFu + ((u >> 16) & 1u);
    u += rounding;
    return (ushort_t)(u >> 16);
}
__device__ __forceinline__ float lo_f(uint_t u) { return __uint_as_float(u << 16); }
__device__ __forceinline__ float hi_f(uint_t u) { return __uint_as_float(u & 0xffff0000u); }
__device__ __forceinline__ uint_t pack2(float a, float b) {
    return (uint_t)f2bf(a) | ((uint_t)f2bf(b) << 16);
}

// is64 detection, inlined per block (wave 0 checks odd words of first 64 ints)
__device__ __forceinline__ int detect64(const int* ei, int* s64) {
    if (threadIdx.x < 64) {
        int v = ei[threadIdx.x];
        bool ok = ((threadIdx.x & 1) == 0) || (v == 0);
        unsigned long long m = __ballot(ok);
        if (threadIdx.x == 0) *s64 = (m == 0xFFFFFFFFFFFFFFFFULL) ? 1 : 0;
    }
    __syncthreads();
    return *s64;
}

// ---------------------------------------------------------------- pass A: per-(block,bucket) histogram
__global__ __launch_bounds__(256) void k_bktcnt(const int* __restrict__ ei,
                                                int* __restrict__ M) {
    __shared__ int cnt[NBKT];
    __shared__ int s64;
    int t = threadIdx.x, blk = blockIdx.x;
    int is64 = detect64(ei, &s64);
    for (int i = t; i < NBKT; i += 256) cnt[i] = 0;
    __syncthreads();
    int e0 = blk * EPB;
    if (is64) {
        const long long* p = (const long long*)ei;
        for (int i = t; i < EPB; i += 256) {
            int d = (int)p[(size_t)NE + e0 + i];
            atomicAdd(&cnt[d >> BKT_SHIFT], 1);
        }
    } else {
        for (int i = t; i < EPB; i += 256) {
            int d = ei[NE + e0 + i];
            atomicAdd(&cnt[d >> BKT_SHIFT], 1);
        }
    }
    __syncthreads();
    for (int i = t; i < NBKT; i += 256) M[i * 256 + blk] = cnt[i];
}

// ---------------------------------------------------------------- per-bucket column scan over 256 blocks
__global__ __launch_bounds__(256) void k_colscan(int* __restrict__ M, int* __restrict__ colsum) {
    __shared__ int sm[256];
    int t = threadIdx.x, b = blockIdx.x;
    int v = M[b * 256 + t];
    sm[t] = v;
    __syncthreads();
    for (int o = 1; o < 256; o <<= 1) {
        int add = (t >= o) ? sm[t - o] : 0;
        __syncthreads();
        sm[t] += add;
        __syncthreads();
    }
    M[b * 256 + t] = sm[t] - v;  // exclusive offset of block t within bucket b
    if (t == 255) colsum[b] = sm[255];
}

// ---------------------------------------------------------------- scan bucket totals -> bkbase[0..NBKT]
__global__ __launch_bounds__(256) void k_bktscan(const int* __restrict__ colsum,
                                                 int* __restrict__ bkbase, int* __restrict__ rs) {
    __shared__ int sm[256];
    int t = threadIdx.x;
    int v = (t < NBKT) ? colsum[t] : 0;
    sm[t] = v;
    __syncthreads();
    for (int o = 1; o < 256; o <<= 1) {
        int add = (t >= o) ? sm[t - o] : 0;
        __syncthreads();
        sm[t] += add;
        __syncthreads();
    }
    if (t <= NBKT) bkbase[t] = sm[t] - v;  // exclusive; bkbase[NBKT] == NE
    if (t == 0) rs[NN] = NE;
}

// ---------------------------------------------------------------- pass B: scatter (src,dst) into bucket regions
__global__ __launch_bounds__(256) void k_bktscatter(const int* __restrict__ ei,
                                                    const int* __restrict__ M,
                                                    const int* __restrict__ bkbase,
                                                    uint2* __restrict__ tmp) {
    __shared__ int cur[NBKT];
    __shared__ int s64;
    int t = threadIdx.x, blk = blockIdx.x;
    int is64 = detect64(ei, &s64);
    for (int i = t; i < NBKT; i += 256) cur[i] = bkbase[i] + M[i * 256 + blk];
    __syncthreads();
    int e0 = blk * EPB;
    if (is64) {
        const long long* p = (const long long*)ei;
        for (int i = t; i < EPB; i += 256) {
            int e = e0 + i;
            int s = (int)p[e], d = (int)p[(size_t)NE + e];
            int pos = atomicAdd(&cur[d >> BKT_SHIFT], 1);
            tmp[pos] = make_uint2((uint_t)s, (uint_t)d);
        }
    } else {
        for (int i = t; i < EPB; i += 256) {
            int e = e0 + i;
            int s = ei[e], d = ei[NE + e];
            int pos = atomicAdd(&cur[d >> BKT_SHIFT], 1);
            tmp[pos] = make_uint2((uint_t)s, (uint_t)d);
        }
    }
}

// ---------------------------------------------------------------- pass C: per-bucket node sort -> rs + esrc
__global__ __launch_bounds__(256) void k_bktsort(const uint2* __restrict__ tmp,
                                                 const int* __restrict__ bkbase,
                                                 int* __restrict__ rs, int* __restrict__ esrc) {
    __shared__ int hist[512];
    __shared__ int curp[512];
    int t = threadIdx.x, b = blockIdx.x;
    int nbase = b << BKT_SHIFT;
    int bb = bkbase[b], be = bkbase[b + 1];
    hist[t] = 0;
    hist[t + 256] = 0;
    __syncthreads();
    for (int i = bb + t; i < be; i += 256)
        atomicAdd(&hist[(int)tmp[i].y - nbase], 1);
    __syncthreads();
    int ov0 = hist[t], ov1 = hist[t + 256];
    for (int o = 1; o < 512; o <<= 1) {
        int v0 = (t >= o) ? hist[t - o] : 0;
        int v1 = (t + 256 >= o) ? hist[t + 256 - o] : 0;
        __syncthreads();
        hist[t] += v0;
        hist[t + 256] += v1;
        __syncthreads();
    }
    int ex0 = bb + hist[t] - ov0;
    int ex1 = bb + hist[t + 256] - ov1;
    int n0 = nbase + t, n1 = nbase + t + 256;
    if (n0 < NN) rs[n0] = ex0;
    if (n1 < NN) rs[n1] = ex1;
    curp[t] = ex0;
    curp[t + 256] = ex1;
    __syncthreads();
    for (int i = bb + t; i < be; i += 256) {
        uint2 pr = tmp[i];
        int pos = atomicAdd(&curp[(int)pr.y - nbase], 1);
        esrc[pos] = (int)pr.x;
    }
}

// ---------------------------------------------------------------- prep: cast x->xb (+zero row), pack W0, pack W1
// blocks [0, 12500]: cast; [12501, 12628]: packW0; [12629, 12692]: packW1
#define CAST_B 12501
__global__ void k_prep(const float* __restrict__ x, ushort_t* __restrict__ xb,
                       const float* __restrict__ Wl0, const float* __restrict__ Wr0,
                       ushort_t* __restrict__ pw0,
                       const float* __restrict__ Wl1, const float* __restrict__ Wr1,
                       ushort_t* __restrict__ pw1) {
    const int n4 = NN * DF / 4;
    int blk = blockIdx.x, t = threadIdx.x;
    if (blk < CAST_B) {
        int i = blk * 256 + t;
        if (i < n4) {
            float4 f = ((const float4*)x)[i];
            uint2 o;
            o.x = pack2(f.x, f.y);
            o.y = pack2(f.z, f.w);
            ((uint2*)xb)[i] = o;
        } else if (i < n4 + 32) {
            ((uint2*)xb)[i] = make_uint2(0u, 0u);  // zero row NN (gather clamp target)
        }
    } else if (blk < CAST_B + 128) {
        // pw0[((s*8+t)*64+lane)*8+j] = (s<4?Wl0:Wr0)[((s&3)*32+quad*8+j)*128 + tt*16+l16]
        int idx = (blk - CAST_B) * 256 + t;  // < 32768
        int j = idx & 7;
        int lane = (idx >> 3) & 63;
        int rem = idx / 512;
        int tt = rem % 8;
        int s = rem / 8;
        int quad = lane >> 4, l16 = lane & 15;
        int k = (s & 3) * 32 + quad * 8 + j;
        int n = tt * 16 + l16;
        const float* W = (s < 4) ? Wl0 : Wr0;
        pw0[idx] = f2bf(W[k * 128 + n]);
    } else {
        // pw1[((s*8+t)*64+lane)*8+j] = (tt<4?Wl1:Wr1)[(s*32+quad*8+j)*64 + (tt&3)*16+l16]
        int idx = (blk - CAST_B - 128) * 256 + t;  // < 16384
        int j = idx & 7;
        int lane = (idx >> 3) & 63;
        int rem = idx / 512;
        int tt = rem % 8;
        int s = rem / 8;
        int quad = lane >> 4, l16 = lane & 15;
        int k = s * 32 + quad * 8 + j;
        int n = (tt & 3) * 16 + l16;
        const float* W = (tt < 4) ? Wl1 : Wr1;
        pw1[idx] = f2bf(W[k * 64 + n]);
    }
}

// ---------------------------------------------------------------- FUSED: gather-mean + gemm0(relu) + gemm2
// One block = 16 nodes = one MFMA M-tile. mean and h live only in LDS.
// Outputs: tbuf[(NN+1) x 64] bf16 (= h @ Wl1), rbuf[NN x 64] f32 (= h @ Wr1 + b1).
__global__ __launch_bounds__(256) void k_fused(const ushort_t* __restrict__ xb,
                                               const int* __restrict__ rs,
                                               const int* __restrict__ esrc,
                                               const ushort_t* __restrict__ pw0,
                                               const float* __restrict__ bl0,
                                               const ushort_t* __restrict__ pw1,
                                               const float* __restrict__ bl1,
                                               ushort_t* __restrict__ tbuf,
                                               float* __restrict__ rbuf) {
    __shared__ ushort_t m_lds[16][136];  // +8 pad: ds_read_b128 A-frags -> 2-way (free)
    __shared__ ushort_t h_lds[16][136];
    int tid = threadIdx.x;
    int wv = tid >> 6, lane = tid & 63;
    int l16 = lane & 15, quad = lane >> 4, gbase = lane & 48;
    int n0 = blockIdx.x * 16;  // NN = 6250*16 exactly

    // ---- phase 1: gather-mean of 4 nodes per wave (16-lane groups), 16 loads in flight
    int n = n0 + wv * 4 + quad;
    int s0 = rs[n];
    int deg = rs[n + 1] - s0;
    int md = deg;
    md = max(md, __shfl_xor(md, 16));
    md = max(md, __shfl_xor(md, 32));
    float acc[8] = {0.f, 0.f, 0.f, 0.f, 0.f, 0.f, 0.f, 0.f};
    const ushort_t* fb = xb + l16 * 8;
    int clampIdx = (deg > 0) ? deg - 1 : 0;
    for (int c = 0; c < md; c += 16) {
        int ii = c + l16;
        if (ii > clampIdx) ii = clampIdx;
        int my = esrc[s0 + ii];
        uint4 v[16];
#pragma unroll
        for (int e = 0; e < 16; e++) {
            int r = __shfl(my, gbase + e);
            r = (c + e < deg) ? r : NN;  // row NN is zero
            v[e] = *(const uint4*)(fb + (size_t)r * DF);
        }
#pragma unroll
        for (int e = 0; e < 16; e++) {
            acc[0] += lo_f(v[e].x); acc[1] += hi_f(v[e].x);
            acc[2] += lo_f(v[e].y); acc[3] += hi_f(v[e].y);
            acc[4] += lo_f(v[e].z); acc[5] += hi_f(v[e].z);
            acc[6] += lo_f(v[e].w); acc[7] += hi_f(v[e].w);
        }
    }
    {
        float inv = 1.0f / (float)(deg > 0 ? deg : 1);
        int nl = wv * 4 + quad;
        uint_t* mp = (uint_t*)&m_lds[nl][l16 * 8];
        mp[0] = pack2(acc[0] * inv, acc[1] * inv);
        mp[1] = pack2(acc[2] * inv, acc[3] * inv);
        mp[2] = pack2(acc[4] * inv, acc[5] * inv);
        mp[3] = pack2(acc[6] * inv, acc[7] * inv);
    }
    __syncthreads();

    // ---- phase 2: gemm0 — rows n0..n0+15, cols wv*32..wv*32+31, K=256 = [mean | xb]
    const int kofs = quad * 8;
    f32x4 c0[2] = {(f32x4){0.f, 0.f, 0.f, 0.f}, (f32x4){0.f, 0.f, 0.f, 0.f}};
#pragma unroll
    for (int s = 0; s < 8; s++) {
        ABFrag a;
        if (s < 4)
            a.u = *(const uint4*)&m_lds[l16][(s & 3) * 32 + kofs];
        else
            a.u = *(const uint4*)(xb + (size_t)(n0 + l16) * DF + (s & 3) * 32 + kofs);
#pragma unroll
        for (int i = 0; i < 2; i++) {
            int t = wv * 2 + i;
            ABFrag b;
            b.u = *(const uint4*)(pw0 + ((size_t)(s * 8 + t) * 64 + lane) * 8);
            c0[i] = __builtin_amdgcn_mfma_f32_16x16x32_bf16(a.v, b.v, c0[i], 0, 0, 0);
        }
    }
#pragma unroll
    for (int i = 0; i < 2; i++) {
        int col = wv * 32 + i * 16 + l16;
        float bv = bl0[col];
#pragma unroll
        for (int r = 0; r < 4; r++) {
            float v = fmaxf(c0[i][r] + bv, 0.f);
            h_lds[quad * 4 + r][col] = f2bf(v);
        }
    }
    __syncthreads();

    // ---- phase 3: gemm2 — [t|r] cols wv*32..wv*32+31, K=128 from h_lds
    f32x4 c1[2] = {(f32x4){0.f, 0.f, 0.f, 0.f}, (f32x4){0.f, 0.f, 0.f, 0.f}};
#pragma unroll
    for (int s = 0; s < 4; s++) {
        ABFrag a;
        a.u = *(const uint4*)&h_lds[l16][s * 32 + kofs];
#pragma unroll
        for (int i = 0; i < 2; i++) {
            int t = wv * 2 + i;
            ABFrag b;
            b.u = *(const uint4*)(pw1 + ((size_t)(s * 8 + t) * 64 + lane) * 8);
            c1[i] = __builtin_amdgcn_mfma_f32_16x16x32_bf16(a.v, b.v, c1[i], 0, 0, 0);
        }
    }
#pragma unroll
    for (int i = 0; i < 2; i++) {
        int t = wv * 2 + i;
        int cc = (t & 3) * 16 + l16;
        if (t < 4) {
#pragma unroll
            for (int r = 0; r < 4; r++)
                tbuf[(size_t)(n0 + quad * 4 + r) * 64 + cc] = f2bf(c1[i][r]);
        } else {
            float bv = bl1[cc];
#pragma unroll
            for (int r = 0; r < 4; r++)
                rbuf[(size_t)(n0 + quad * 4 + r) * 64 + cc] = c1[i][r] + bv;
        }
    }
    if (blockIdx.x == 0 && tid < 32)
        ((uint_t*)(tbuf + (size_t)NN * 64))[tid] = 0u;  // zero row NN for agg2 clamp
}

// ---------------------------------------------------------------- layer-1 final: out = mean(gather(t)) + r
// 8 nodes per wave (8-lane groups); t rows 128 B; 8 loads in flight.
__global__ __launch_bounds__(256) void k_agg2(const ushort_t* __restrict__ tbuf,
                                              const float* __restrict__ rbuf,
                                              const int* __restrict__ rs,
                                              const int* __restrict__ esrc,
                                              float* __restrict__ out) {
    int wv = threadIdx.x >> 6;
    int lane = threadIdx.x & 63;
    int li = lane & 7;
    int gbase = lane & 56;
    int n = (blockIdx.x * 4 + wv) * 8 + (lane >> 3);  // 32 nodes/block; NN = 3125*32 exactly
    int s0 = rs[n];
    int deg = rs[n + 1] - s0;
    int md = deg;
    md = max(md, __shfl_xor(md, 8));
    md = max(md, __shfl_xor(md, 16));
    md = max(md, __shfl_xor(md, 32));
    float acc[8] = {0.f, 0.f, 0.f, 0.f, 0.f, 0.f, 0.f, 0.f};
    const ushort_t* fb = tbuf + li * 8;
    int clampIdx = (deg > 0) ? deg - 1 : 0;
    for (int c = 0; c < md; c += 8) {
        int ii = c + li;
        if (ii > clampIdx) ii = clampIdx;
        int my = esrc[s0 + ii];
        uint4 v[8];
#pragma unroll
        for (int e = 0; e < 8; e++) {
            int r = __shfl(my, gbase + e);
            r = (c + e < deg) ? r : NN;  // row NN is zero
            v[e] = *(const uint4*)(fb + (size_t)r * 64);
        }
#pragma unroll
        for (int e = 0; e < 8; e++) {
            acc[0] += lo_f(v[e].x); acc[1] += hi_f(v[e].x);
            acc[2] += lo_f(v[e].y); acc[3] += hi_f(v[e].y);
            acc[4] += lo_f(v[e].z); acc[5] += hi_f(v[e].z);
            acc[6] += lo_f(v[e].w); acc[7] += hi_f(v[e].w);
        }
    }
    float inv = 1.0f / (float)(deg > 0 ? deg : 1);
    const float4* rp = (const float4*)(rbuf + (size_t)n * 64 + li * 8);
    float4 ra = rp[0], rb = rp[1];
    float4 oa, ob;
    oa.x = acc[0] * inv + ra.x; oa.y = acc[1] * inv + ra.y;
    oa.z = acc[2] * inv + ra.z; oa.w = acc[3] * inv + ra.w;
    ob.x = acc[4] * inv + rb.x; ob.y = acc[5] * inv + rb.y;
    ob.z = acc[6] * inv + rb.z; ob.w = acc[7] * inv + rb.w;
    float4* op = (float4*)(out + (size_t)n * 64 + li * 8);
    op[0] = oa;
    op[1] = ob;
}

// ---------------------------------------------------------------- launcher
extern "C" void kernel_launch(void* const* d_in, const int* in_sizes, int n_in,
                              void* d_out, int out_size, void* d_ws, size_t ws_size,
                              hipStream_t stream) {
    const float* x   = (const float*)d_in[0];
    const int*   ei  = (const int*)d_in[1];
    const float* Wl0 = (const float*)d_in[2];
    const float* bl0 = (const float*)d_in[3];
    const float* Wr0 = (const float*)d_in[4];
    const float* Wl1 = (const float*)d_in[5];
    const float* bl1 = (const float*)d_in[6];
    const float* Wr1 = (const float*)d_in[7];
    float* out = (float*)d_out;

    char* ws = (char*)d_ws;
    size_t off = 0;
    auto alloc = [&](size_t b) {
        size_t o = off;
        off += (b + 255) & ~(size_t)255;
        return o;
    };
    int* rs     = (int*)(ws + alloc((size_t)(NN + 1) * 4));
    int* M      = (int*)(ws + alloc((size_t)NBKT * 256 * 4));
    int* colsum = (int*)(ws + alloc((size_t)NBKT * 4));
    int* bkbase = (int*)(ws + alloc((size_t)(NBKT + 1) * 4));
    int* esrc   = (int*)(ws + alloc((size_t)NE * 4));
    ushort_t* pw0  = (ushort_t*)(ws + alloc((size_t)8 * 8 * 512 * 2));
    ushort_t* pw1  = (ushort_t*)(ws + alloc((size_t)4 * 8 * 512 * 2));
    ushort_t* xb   = (ushort_t*)(ws + alloc((size_t)(NN + 1) * DF * 2));   // +1 zero row
    ushort_t* tbuf = (ushort_t*)(ws + alloc((size_t)(NN + 1) * 64 * 2));   // +1 zero row
    float*    rbuf = (float*)(ws + alloc((size_t)NN * 64 * 4));
    // tmp (12.8MB, bktscatter->bktsort) aliases rbuf (25.6MB, first written by k_fused later)
    uint2* tmp = (uint2*)rbuf;

    k_bktcnt<<<256, 256, 0, stream>>>(ei, M);
    k_colscan<<<NBKT, 256, 0, stream>>>(M, colsum);
    k_bktscan<<<1, 256, 0, stream>>>(colsum, bkbase, rs);
    k_bktscatter<<<256, 256, 0, stream>>>(ei, M, bkbase, tmp);
    k_bktsort<<<NBKT, 256, 0, stream>>>(tmp, bkbase, rs, esrc);
    k_prep<<<CAST_B + 128 + 64, 256, 0, stream>>>(x, xb, Wl0, Wr0, pw0, Wl1, Wr1, pw1);
    k_fused<<<NN / 16, 256, 0, stream>>>(xb, rs, esrc, pw0, bl0, pw1, bl1, tbuf, rbuf);
    k_agg2<<<NN / 32, 256, 0, stream>>>(tbuf, rbuf, rs, esrc, out);
}